// Round 4
// baseline (3619.173 us; speedup 1.0000x reference)
//
#include <hip/hip_runtime.h>

typedef unsigned short u16;
typedef unsigned int u32;
typedef __attribute__((ext_vector_type(4))) float f32x4;
typedef __attribute__((ext_vector_type(8))) short s16x8;
typedef __attribute__((ext_vector_type(4))) int i32x4;

#define EPS 1e-5f

// ---------- helpers ----------
__device__ __forceinline__ u16 f2bf(float f) {
  unsigned u = __float_as_uint(f);
  return (u16)((u + 0x7fffu + ((u >> 16) & 1u)) >> 16);
}
__device__ __forceinline__ float sigm(float x) { return 1.0f / (1.0f + __expf(-x)); }
__device__ __forceinline__ float tanh_f(float x) {
  float e = __expf(-2.0f * fabsf(x));
  float r = (1.0f - e) / (1.0f + e);
  return copysignf(r, x);
}
__device__ __forceinline__ void gl_lds16(const void* g, void* l) {
  __builtin_amdgcn_global_load_lds(
      (const __attribute__((address_space(1))) u32*)g,
      (__attribute__((address_space(3))) u32*)l, 16, 0, 0);
}

// ---------- weight pack: conv_w (512,192,5) f32 -> per-fragment bf16 ----------
// f = (tap*6+kk)*32 + of ; of = o>>4 ; element = lane*8+j
// A[o][c]: o = of*16 + (lane&15), c = kk*32 + (lane>>4)*8 + j
__global__ __launch_bounds__(256) void k_wcvt(const float* __restrict__ w, u16* __restrict__ Wpk) {
  int idx = blockIdx.x * 256 + threadIdx.x;   // exactly 491520 threads
  int f = idx >> 9, r = idx & 511;
  int lane = r >> 3, j = r & 7;
  int of = f & 31, tk = f >> 5;
  int kk = tk % 6, tap = tk / 6;
  int o = (of << 4) + (lane & 15);
  int c = (kk << 5) + ((lane >> 4) << 3) + j;
  Wpk[idx] = f2bf(w[(o * 192 + c) * 5 + tap]);
}

// ---------- x transpose: inputs (t,b,64,256) f32 -> xT[t*32+b][264 rows][64 c] bf16, swizzled ----------
__global__ __launch_bounds__(256) void k_xtrans(const float* __restrict__ x, u16* __restrict__ xT) {
  int tb = blockIdx.x;
  int tid = threadIdx.x;
  __shared__ __align__(16) u16 ltile[256 * 72];
  const float* src = x + tb * (64 * 256);
  for (int it = 0; it < 64; ++it) {
    int idx = it * 256 + tid;
    int c = idx >> 8, l = idx & 255;
    ltile[l * 72 + c] = f2bf(src[idx]);
  }
  __syncthreads();
  char* dst = (char*)(xT + tb * 16896);   // 264*64 u16 = 33792 B
  i32x4 z = {0, 0, 0, 0};
  for (int i = tid; i < 2112; i += 256) { // 264 rows * 8 chunks
    int r = i >> 3, ch = i & 7;
    i32x4 v = z;
    if (r >= 2 && r < 258) v = *(const i32x4*)(ltile + (r - 2) * 72 + ch * 8);
    *(i32x4*)(dst + r * 128 + ((ch * 16) ^ ((r & 7) << 4))) = v;
  }
}

// ---------- zero h-state (both buffers) + flags + barrier ----------
__global__ void k_init(i32x4* __restrict__ hT, i32x4* __restrict__ flg) {
  int n = gridDim.x * blockDim.x;
  int tid = blockIdx.x * blockDim.x + threadIdx.x;
  i32x4 z = {0, 0, 0, 0};
  for (int i = tid; i < 270336; i += n) hT[i] = z;   // 2 x 32*264*128 u16
  for (int i = tid; i < 2052;   i += n) flg[i] = z;  // 8192 flags + barrier
}

// ---------- mega kernel: all 32 steps, in-kernel grid sync ----------
// grid 256 = b(32) x chs(8); block 512 = 8 waves = ks(2 K-halves) x wcol(4 L-quarters)
// Block tile: 64 gate-M (4 gates x 16 hy-ch) x 256 L; wave: 64x64 x K/2.
__global__ __launch_bounds__(512, 2) void k_mega(
    const u16* __restrict__ Wpk, const u16* __restrict__ xT, u16* __restrict__ hT,
    const float* __restrict__ cb, const float* __restrict__ gnw, const float* __restrict__ gnb,
    float* __restrict__ out, float* __restrict__ stats, int* __restrict__ flags,
    int* __restrict__ bar) {
  const int bid = blockIdx.x;
  const int b = bid >> 3, chs = bid & 7;
  const int tid = threadIdx.x;
  const int wave = tid >> 6, lane = tid & 63;
  const int ks = wave >> 2, wcol = wave & 3;
  const int cgrp = (lane >> 4) << 4;
  const int ch16 = (lane >> 4) << 2;
  const int l15 = lane & 15;

  __shared__ __align__(16) char ldsx[33792];   // 264 rows x 128 B (x, swizzled)
  __shared__ __align__(16) char ldsh[67584];   // 264 rows x 256 B (h, swizzled); reused as acc-exchange
  __shared__ __align__(16) char hl[8192];      // 256 L x 32 B (16 ch bf16)
  __shared__ float red[8][4][2];
  __shared__ float smu[4], srs[4];

  // step-invariant per-thread params (kept channels: chs*16 + ch16 + r)
  f32x4 biasv[4], wgn[4], bgn[4];
  #pragma unroll
  for (int g = 0; g < 4; ++g) {
    biasv[g] = *(const f32x4*)(cb  + (g << 7) + (chs << 4) + ch16);
    wgn[g]   = *(const f32x4*)(gnw + (g << 7) + (chs << 4) + ch16);
    bgn[g]   = *(const f32x4*)(gnb + (g << 7) + (chs << 4) + ch16);
  }
  float cxr[2][4];
  #pragma unroll
  for (int q = 0; q < 2; ++q)
    #pragma unroll
    for (int r = 0; r < 4; ++r) cxr[q][r] = 0.f;

  // ---- stage x(0), h(0) ----
  {
    const char* xs = (const char*)(xT + b * 16896);
    for (int i = tid; i < 2112; i += 512) gl_lds16(xs + (i << 4), ldsx + ((i >> 6) << 10));
    const char* hs = (const char*)hT + b * 67584;   // buffer 0 (zeroed)
    for (int i = tid; i < 4224; i += 512) gl_lds16(hs + (i << 4), ldsh + ((i >> 6) << 10));
  }
  asm volatile("s_waitcnt vmcnt(0)" ::: "memory");
  __syncthreads();

  #pragma unroll 1
  for (int t = 0; t < 32; ++t) {
    // ---- K-loop: 15 chunks for this ks-half, no barriers, A direct from global ----
    f32x4 zero4 = {0.f, 0.f, 0.f, 0.f};
    f32x4 acc[4][4];
    #pragma unroll
    for (int g = 0; g < 4; ++g)
      #pragma unroll
      for (int ni = 0; ni < 4; ++ni) acc[g][ni] = zero4;

    const int cc0 = ks * 15;
    #pragma unroll 3
    for (int c = 0; c < 15; ++c) {
      const int cc = cc0 + c;
      const int tap = (cc * 43) >> 8;          // cc/6 for cc<30
      const int kk = cc - tap * 6;
      s16x8 av[4];
      #pragma unroll
      for (int g = 0; g < 4; ++g)
        av[g] = *(const s16x8*)((const char*)Wpk +
                 (((cc << 5) + (g << 3) + chs) << 10) + (lane << 4));
      s16x8 bvf[4];
      #pragma unroll
      for (int ni = 0; ni < 4; ++ni) {
        const int row = (wcol << 6) + (ni << 4) + l15 + tap;
        const int sw = (row & 7) << 4;
        bvf[ni] = (kk < 2)
          ? *(const s16x8*)(ldsx + (row << 7) + (((kk << 6) + cgrp) ^ sw))
          : *(const s16x8*)(ldsh + (row << 8) + ((((kk - 2) << 6) + cgrp) ^ sw));
      }
      #pragma unroll
      for (int g = 0; g < 4; ++g)
        #pragma unroll
        for (int ni = 0; ni < 4; ++ni)
          acc[g][ni] = __builtin_amdgcn_mfma_f32_16x16x32_bf16(av[g], bvf[ni], acc[g][ni], 0, 0, 0);
    }
    __syncthreads();   // (A) all waves done reading ldsx/ldsh

    // ---- symmetric k-split exchange: give away the other half's ni pair via ldsh ----
    {
      const int oks = 1 - ks;
      #pragma unroll
      for (int g = 0; g < 4; ++g)
        #pragma unroll
        for (int q = 0; q < 2; ++q)
          *(f32x4*)(ldsh + (wave << 13) + (((g << 1) + q) << 10) + (lane << 4)) =
              acc[g][(oks << 1) + q];
    }
    // prefetch x(t+1) into ldsx (overlaps epilogue)
    if (t < 31) {
      const char* xs = (const char*)(xT + (((t + 1) << 5) + b) * 16896);
      for (int i = tid; i < 2112; i += 512) gl_lds16(xs + (i << 4), ldsx + ((i >> 6) << 10));
    }
    __syncthreads();   // (B)

    // ---- merge partner partials into kept cells; +bias; per-gate stats ----
    float sum[4], sq[4];
    const int pw = wave ^ 4;
    #pragma unroll
    for (int g = 0; g < 4; ++g) {
      sum[g] = 0.f; sq[g] = 0.f;
      #pragma unroll
      for (int q = 0; q < 2; ++q) {
        const int ni = (ks << 1) + q;
        f32x4 v = *(const f32x4*)(ldsh + (pw << 13) + (((g << 1) + q) << 10) + (lane << 4));
        #pragma unroll
        for (int r = 0; r < 4; ++r) {
          float x = v[r] + acc[g][ni][r] + biasv[g][r];
          v[r] = x; sum[g] += x; sq[g] += x * x;
        }
        acc[g][ni] = v;
      }
    }
    #pragma unroll
    for (int off = 1; off < 64; off <<= 1) {
      #pragma unroll
      for (int g = 0; g < 4; ++g) {
        sum[g] += __shfl_xor(sum[g], off);
        sq[g]  += __shfl_xor(sq[g], off);
      }
    }
    if (lane == 0) {
      #pragma unroll
      for (int g = 0; g < 4; ++g) { red[wave][g][0] = sum[g]; red[wave][g][1] = sq[g]; }
    }
    __syncthreads();   // (C)

    // ---- partner-block (chs^1) stats exchange ----
    const int slot = (((t << 5) + b) << 3) + chs;
    if (tid == 0) {
      #pragma unroll
      for (int g = 0; g < 4; ++g) {
        float s = 0.f, q = 0.f;
        #pragma unroll
        for (int w = 0; w < 8; ++w) { s += red[w][g][0]; q += red[w][g][1]; }
        __hip_atomic_store(&stats[(slot << 3) + (g << 1)], s, __ATOMIC_RELAXED, __HIP_MEMORY_SCOPE_AGENT);
        __hip_atomic_store(&stats[(slot << 3) + (g << 1) + 1], q, __ATOMIC_RELAXED, __HIP_MEMORY_SCOPE_AGENT);
      }
      __hip_atomic_store(&flags[slot], 1, __ATOMIC_RELEASE, __HIP_MEMORY_SCOPE_AGENT);
      while (__hip_atomic_load(&flags[slot ^ 1], __ATOMIC_ACQUIRE, __HIP_MEMORY_SCOPE_AGENT) == 0)
        __builtin_amdgcn_s_sleep(1);
    }
    __syncthreads();   // (D)
    if (tid < 4) {     // g = tid; fixed order even+odd -> identical in both partners
      const int base = (slot >> 1) << 4;
      float s = __hip_atomic_load(&stats[base + (tid << 1)], __ATOMIC_RELAXED, __HIP_MEMORY_SCOPE_AGENT)
              + __hip_atomic_load(&stats[base + 8 + (tid << 1)], __ATOMIC_RELAXED, __HIP_MEMORY_SCOPE_AGENT);
      float q = __hip_atomic_load(&stats[base + (tid << 1) + 1], __ATOMIC_RELAXED, __HIP_MEMORY_SCOPE_AGENT)
              + __hip_atomic_load(&stats[base + 8 + (tid << 1) + 1], __ATOMIC_RELAXED, __HIP_MEMORY_SCOPE_AGENT);
      const float inv = 1.0f / 8192.0f;
      float m = s * inv;
      smu[tid] = m;
      srs[tid] = rsqrtf(q * inv - m * m + EPS);
    }
    __syncthreads();   // (E)

    // ---- GN apply + LSTM pointwise on kept cells; cx in registers ----
    float mu0 = smu[0], mu1 = smu[1], mu2 = smu[2], mu3 = smu[3];
    float rs0 = srs[0], rs1 = srs[1], rs2 = srs[2], rs3 = srs[3];
    float* outp = out + (((t << 5) + b) << 15);
    #pragma unroll
    for (int q = 0; q < 2; ++q) {
      const int ni = (ks << 1) + q;
      const int l = (wcol << 6) + (ni << 4) + l15;
      u16 hp[4];
      #pragma unroll
      for (int r = 0; r < 4; ++r) {
        const int c = (chs << 4) + ch16 + r;   // hy channel
        float vi = (acc[0][ni][r] - mu0) * rs0 * wgn[0][r] + bgn[0][r];
        float vf = (acc[1][ni][r] - mu1) * rs1 * wgn[1][r] + bgn[1][r];
        float vg = (acc[2][ni][r] - mu2) * rs2 * wgn[2][r] + bgn[2][r];
        float vo = (acc[3][ni][r] - mu3) * rs3 * wgn[3][r] + bgn[3][r];
        float cyv = sigm(vf) * cxr[q][r] + sigm(vi) * tanh_f(vg);
        float hyv = sigm(vo) * tanh_f(cyv);
        cxr[q][r] = cyv;
        outp[(c << 8) + l] = hyv;
        hp[r] = f2bf(hyv);
        if (t == 31) {
          const int cxi = (((b << 7) + c) << 8) + l;
          out[33554432 + cxi] = hyv;   // final hy
          out[34603008 + cxi] = cyv;   // final cy
        }
      }
      *(unsigned long long*)(hl + (l << 5) + ((ch16 << 1) ^ ((l & 1) << 4))) =
          *(const unsigned long long*)hp;
    }
    __syncthreads();   // (F)

    // ---- transposed h write: 16-ch stripe -> hTw (swizzled rows) ----
    {
      u16* hTw = hT + ((t + 1) & 1) * 1081344;
      const int l = tid >> 1, k = tid & 1;
      const int row = l + 2;
      i32x4 v = *(const i32x4*)(hl + (l << 5) + ((k << 4) ^ ((l & 1) << 4)));
      *(i32x4*)((char*)hTw + b * 67584 + (row << 8) +
                ((((chs << 1) + k) << 4) ^ ((row & 7) << 4))) = v;
    }

    if (t < 31) {
      __threadfence();
      // ---- grid sync (256 blocks, all resident: 110KB LDS -> 1 block/CU) ----
      __syncthreads();
      if (tid == 0) {
        int arr = __hip_atomic_fetch_add(&bar[0], 1, __ATOMIC_ACQ_REL, __HIP_MEMORY_SCOPE_AGENT);
        if (arr == 255) {
          __hip_atomic_store(&bar[0], 0, __ATOMIC_RELAXED, __HIP_MEMORY_SCOPE_AGENT);
          __hip_atomic_store(&bar[1], t + 1, __ATOMIC_RELEASE, __HIP_MEMORY_SCOPE_AGENT);
        } else {
          while (__hip_atomic_load(&bar[1], __ATOMIC_ACQUIRE, __HIP_MEMORY_SCOPE_AGENT) <= t)
            __builtin_amdgcn_s_sleep(1);
        }
      }
      __syncthreads();
      // ---- stage h(t+1) ----
      const char* hs = (const char*)(hT + ((t + 1) & 1) * 1081344) + b * 67584;
      for (int i = tid; i < 4224; i += 512) gl_lds16(hs + (i << 4), ldsh + ((i >> 6) << 10));
      asm volatile("s_waitcnt vmcnt(0)" ::: "memory");
      __syncthreads();
    }
  }
}

// ---------- launch ----------
extern "C" void kernel_launch(void* const* d_in, const int* in_sizes, int n_in,
                              void* d_out, int out_size, void* d_ws, size_t ws_size,
                              hipStream_t stream) {
  const float* x  = (const float*)d_in[0];
  const float* cw = (const float*)d_in[1];
  const float* cb = (const float*)d_in[2];
  const float* gw = (const float*)d_in[3];
  const float* gb = (const float*)d_in[4];
  float* out = (float*)d_out;
  char* ws = (char*)d_ws;

  u16*   Wpk   = (u16*)(ws);                 //     983,040 B
  u16*   xT    = (u16*)(ws + 983040);        //  34,603,008 B
  u16*   hT    = (u16*)(ws + 35586048);      //   4,325,376 B (ping-pong)
  float* stats = (float*)(ws + 39911424);    //     262,144 B
  int*   flags = (int*)(ws + 40173568);      //      32,768 B
  int*   bar   = (int*)(ws + 40206336);      //          16 B  (~40.2 MB)

  k_wcvt<<<1920, 256, 0, stream>>>(cw, Wpk);
  k_xtrans<<<1024, 256, 0, stream>>>(x, xT);
  k_init<<<256, 256, 0, stream>>>((i32x4*)hT, (i32x4*)flags);
  k_mega<<<256, 512, 0, stream>>>(Wpk, xT, hT, cb, gw, gb, out, stats, flags, bar);
}